// Round 3
// baseline (1579.117 us; speedup 1.0000x reference)
//
#include <hip/hip_runtime.h>
#include <hip/hip_fp16.h>

// B=64, N=64, D=128, L=4, T=10. Float tensors may arrive as bf16 OR fp32.
// r15: SINGLE-dispatch, zero-sync design. Lessons from r14's counters:
//   - agent-scope release/acquire sync emits sc1 L2 writeback/invalidate ->
//     FETCH_SIZE 10.6MB (12x refetch), in-loop reads at HBM latency. So:
//     NO cross-block communication at all.
//   - dispatch overhead ~15us each (explains r13: 10 dispatches = 216us with
//     only ~65us of kernel time). So: ONE dispatch.
// Block = one batch (64 blocks x 1024 threads = 16 waves). h/a/b/m live in
// LDS; each block swizzles its own weight tiles from raw global into a 32KB
// LDS slab per phase (weights are L2-resident, read coalesced). Edge S-tiles
// are built directly in MFMA A-fragment registers (no S LDS, no per-i
// barriers). All math verbatim from the proven r10/r13 kernels.

typedef _Float16 f16;
typedef _Float16 f16x4 __attribute__((ext_vector_type(4)));
typedef _Float16 f16x8 __attribute__((ext_vector_type(8)));
typedef float f32x4 __attribute__((ext_vector_type(4)));

union H2x4 { f16x8 v; __half2 h[4]; };

__device__ __forceinline__ float bf2f(unsigned short u) {
    union { unsigned int i; float f; } v; v.i = ((unsigned int)u) << 16; return v.f;
}
__device__ __forceinline__ unsigned short f2bf(float f) {
    union { float f; unsigned int i; } v; v.f = f;
    unsigned int x = v.i;
    return (unsigned short)((x + 0x7fffu + ((x >> 16) & 1u)) >> 16);
}
__device__ __forceinline__ float silu_f(float x) {
    float e = __builtin_amdgcn_exp2f(-1.44269504088896f * x);
    return x * __builtin_amdgcn_rcpf(1.0f + e);
}
__device__ __forceinline__ __half2 silu_h2(__half2 x, __half2 kf, __half2 one2) {
    __half2 e = h2exp2(__hmul2(x, kf));
    return __hmul2(x, h2rcp(__hadd2(one2, e)));
}

struct Ptrs { const void* p[14]; };
// p: 0 pos, 1 embed, 2 ew1, 3 eb1, 4 ew2, 5 eb2, 6 nw1, 7 nb1, 8 nw2,
//    9 nb2, 10 lng, 11 lnb, 12 ow, 13 ob

__device__ __forceinline__ float ldf(const void* p, int i, int bf) {
    return bf ? bf2f(((const unsigned short*)p)[i]) : ((const float*)p)[i];
}

// Stage one 128x128 fp32/bf16 matrix (row-major, ld=128, element offset
// `base`) into B-fragment order for mfma_f32_16x16x32_f16:
//   frag[((s*8+c)*64 + l)*8 + j] = W[s*32 + (l>>4)*8 + j][c*16 + (l&15)]
// Thread t handles a 4x4 tile: coalesced f32x4/ushort4 row reads, packed
// ds_write_b64 along the contiguous j direction.
__device__ __forceinline__ void stage_w(const void* W, int base, int bfflag,
                                        f16* slab, int t)
{
    int rq = t >> 5, cq = t & 31;
    int row0 = rq << 2, col0 = cq << 2;
    float v[4][4];
    if (bfflag) {
        const unsigned short* p = (const unsigned short*)W + base;
#pragma unroll
        for (int r = 0; r < 4; r++) {
            ushort4 u = *(const ushort4*)(p + (row0 + r) * 128 + col0);
            v[r][0] = bf2f(u.x); v[r][1] = bf2f(u.y);
            v[r][2] = bf2f(u.z); v[r][3] = bf2f(u.w);
        }
    } else {
        const float* p = (const float*)W + base;
#pragma unroll
        for (int r = 0; r < 4; r++) {
            f32x4 u = *(const f32x4*)(p + (row0 + r) * 128 + col0);
            v[r][0] = u[0]; v[r][1] = u[1]; v[r][2] = u[2]; v[r][3] = u[3];
        }
    }
    int s = row0 >> 5, q = (row0 >> 3) & 3, j0 = row0 & 7;
    int c = col0 >> 4, colin = col0 & 15;
    f16* dstb = slab + (((s * 8 + c) * 64 + q * 16 + colin) * 8 + j0);
#pragma unroll
    for (int cc = 0; cc < 4; cc++) {
        f16x4 pk = { (f16)v[0][cc], (f16)v[1][cc], (f16)v[2][cc], (f16)v[3][cc] };
        *(f16x4*)(dstb + cc * 8) = pk;
    }
}

#define LS 136   // LDS row stride (f16): 272 B, 16B-aligned, conflict-benign

__global__ __launch_bounds__(1024) void net_kernel(
    Ptrs ptrs, const int* an, void* out)
{
    __shared__ f16 h_lds[64 * LS];
    __shared__ f16 a_lds[64 * LS];
    __shared__ f16 b_lds[64 * LS];
    __shared__ f16 m_lds[64 * LS];
    __shared__ f16 Wslab[16384];        // 32 KB staging slab
    __shared__ f16 wd16[128];
    __shared__ float bias[768];         // eb2,nb1,nb2,lng,lnb,eb1next
    __shared__ float dsq_psh[2048];     // dsq (as half[4096]); psh in final
    __shared__ float s1sh[8][64], s2sh[8][64];
    __shared__ int flgsh;

    int t = threadIdx.x;
    int b = blockIdx.x;
    int w = t >> 6, lane = t & 63;
    int m_ = lane & 15, q_ = lane >> 4;
    __half* dsqh = (__half*)dsq_psh;

    if (t < 64) {
        int ex = (((const unsigned short*)ptrs.p[0])[t * 2] >> 7) & 0xFF;
        unsigned long long mk = __ballot(ex >= 110 && ex <= 135);
        if (t == 0) flgsh = (__popcll(mk) >= 40) ? 1 : 0;
    }
    __syncthreads();
    const int bf = flgsh;

    // dist^2 (layer-invariant) + embed -> h_lds
    for (int k = t; k < 4096; k += 1024) {
        int i = k >> 6, j = k & 63;
        int gi = b * 64 + i, gj = b * 64 + j;
        float dx = ldf(ptrs.p[0], gi * 3 + 0, bf) - ldf(ptrs.p[0], gj * 3 + 0, bf);
        float dy = ldf(ptrs.p[0], gi * 3 + 1, bf) - ldf(ptrs.p[0], gj * 3 + 1, bf);
        float dz = ldf(ptrs.p[0], gi * 3 + 2, bf) - ldf(ptrs.p[0], gj * 3 + 2, bf);
        dsqh[k] = __float2half_rn(dx * dx + dy * dy + dz * dz);
    }
    {
        int row = t & 63, ch = t >> 6;     // ch 0..15: cols ch*8..+7
        int a = an[b * 64 + row];
        a = a < 0 ? 0 : (a > 9 ? 9 : a);
        f16x8 hv;
#pragma unroll
        for (int e = 0; e < 8; e++)
            hv[e] = (f16)ldf(ptrs.p[1], a * 128 + ch * 8 + e, bf);
        *(f16x8*)(h_lds + row * LS + ch * 8) = hv;
    }
    __syncthreads();

    int mbh = w >> 3, ct = w & 7;          // node-phase tile assignment

    // ---- init: a^0 = h@wa + eb1[0] ; b^0 = h@wb ----
    stage_w(ptrs.p[2], 0, bf, Wslab, t);
    __syncthreads();
    {
        f32x4 acc[2];
#pragma unroll
        for (int tt = 0; tt < 2; tt++) {
            float e = ldf(ptrs.p[3], ct * 16 + m_, bf);
            acc[tt] = (f32x4){ e, e, e, e };
            int mb = mbh * 2 + tt;
#pragma unroll
            for (int s = 0; s < 4; s++) {
                f16x8 hf = *(const f16x8*)(h_lds + (mb * 16 + m_) * LS + s * 32 + q_ * 8);
                f16x8 wf = *(const f16x8*)(Wslab + ((s * 8 + ct) * 64 + lane) * 8);
                acc[tt] = __builtin_amdgcn_mfma_f32_16x16x32_f16(hf, wf, acc[tt], 0, 0, 0);
            }
#pragma unroll
            for (int r = 0; r < 4; r++)
                a_lds[(mb * 16 + q_ * 4 + r) * LS + ct * 16 + m_] = (f16)acc[tt][r];
        }
    }
    __syncthreads();
    stage_w(ptrs.p[2], 16384, bf, Wslab, t);
    __syncthreads();
    {
        f32x4 acc[2];
#pragma unroll
        for (int tt = 0; tt < 2; tt++) {
            acc[tt] = (f32x4){ 0.f, 0.f, 0.f, 0.f };
            int mb = mbh * 2 + tt;
#pragma unroll
            for (int s = 0; s < 4; s++) {
                f16x8 hf = *(const f16x8*)(h_lds + (mb * 16 + m_) * LS + s * 32 + q_ * 8);
                f16x8 wf = *(const f16x8*)(Wslab + ((s * 8 + ct) * 64 + lane) * 8);
                acc[tt] = __builtin_amdgcn_mfma_f32_16x16x32_f16(hf, wf, acc[tt], 0, 0, 0);
            }
#pragma unroll
            for (int r = 0; r < 4; r++)
                b_lds[(mb * 16 + q_ * 4 + r) * LS + ct * 16 + m_] = (f16)acc[tt][r];
        }
    }
    __syncthreads();

    // ---- layers ----
#pragma unroll 1
    for (int lay = 0; lay < 4; lay++) {
        // stage ew2 + per-layer small vectors
        stage_w(ptrs.p[4], lay * 16384, bf, Wslab, t);
        if (t < 768) {
            int v = t >> 7, e = t & 127;
            if      (v == 0) bias[t] = ldf(ptrs.p[5],  lay * 128 + e, bf);
            else if (v == 1) bias[t] = ldf(ptrs.p[7],  lay * 128 + e, bf);
            else if (v == 2) bias[t] = ldf(ptrs.p[9],  lay * 128 + e, bf);
            else if (v == 3) bias[t] = ldf(ptrs.p[10], lay * 128 + e, bf);
            else if (v == 4) bias[t] = ldf(ptrs.p[11], lay * 128 + e, bf);
            else if (lay < 3) bias[t] = ldf(ptrs.p[3], (lay + 1) * 128 + e, bf);
        } else if (t < 896) {
            int e = t - 768;
            wd16[e] = (f16)ldf(ptrs.p[2], lay * 32896 + 32768 + e, bf);
        }
        __syncthreads();

        // ---- edge: wave w owns i = w*4 .. w*4+3; S built in A-frag regs ----
        {
            f16x8 wdf[4];
#pragma unroll
            for (int s = 0; s < 4; s++)
                wdf[s] = *(const f16x8*)(wd16 + s * 32 + q_ * 8);
            float eb2v[8];
#pragma unroll
            for (int c = 0; c < 8; c++) eb2v[c] = bias[c * 16 + m_];
            const __half2 kf   = __floats2half2_rn(-1.44269504f, -1.44269504f);
            const __half2 one2 = __floats2half2_rn(1.0f, 1.0f);
#pragma unroll 1
            for (int ii = 0; ii < 4; ii++) {
                int i = w * 4 + ii;
                f16x8 af[4];
#pragma unroll
                for (int s = 0; s < 4; s++)
                    af[s] = *(const f16x8*)(a_lds + i * LS + s * 32 + q_ * 8);
                float msum[8] = { 0.f, 0.f, 0.f, 0.f, 0.f, 0.f, 0.f, 0.f };
#pragma unroll
                for (int mb = 0; mb < 4; mb++) {
                    __half dh = dsqh[i * 64 + mb * 16 + m_];
                    __half2 ds2 = __halves2half2(dh, dh);
                    f16x8 sf[4];
#pragma unroll
                    for (int s = 0; s < 4; s++) {
                        H2x4 bv, av, wv, sv;
                        bv.v = *(const f16x8*)(b_lds + (mb * 16 + m_) * LS + s * 32 + q_ * 8);
                        av.v = af[s];
                        wv.v = wdf[s];
#pragma unroll
                        for (int e = 0; e < 4; e++) {
                            __half2 pre = __hfma2(ds2, wv.h[e],
                                                  __hadd2(av.h[e], bv.h[e]));
                            sv.h[e] = silu_h2(pre, kf, one2);
                        }
                        sf[s] = sv.v;
                    }
#pragma unroll
                    for (int c = 0; c < 8; c++) {
                        f32x4 acc = { eb2v[c], eb2v[c], eb2v[c], eb2v[c] };
#pragma unroll
                        for (int s = 0; s < 4; s++) {
                            f16x8 wf = *(const f16x8*)(Wslab + ((s * 8 + c) * 64 + lane) * 8);
                            acc = __builtin_amdgcn_mfma_f32_16x16x32_f16(sf[s], wf, acc, 0, 0, 0);
                        }
                        msum[c] += silu_f(acc[0]) + silu_f(acc[1])
                                 + silu_f(acc[2]) + silu_f(acc[3]);
                    }
                }
#pragma unroll
                for (int c = 0; c < 8; c++) {
                    float red = msum[c];
                    red += __shfl_xor(red, 16);
                    red += __shfl_xor(red, 32);
                    if (q_ == 0)
                        m_lds[i * LS + c * 16 + m_] = (f16)(red * 0.015625f);
                }
            }
        }
        __syncthreads();

        // ---- node ----
        stage_w(ptrs.p[6], lay * 32768, bf, Wslab, t);       // nw1 h-part
        __syncthreads();
        float nb1v = bias[128 + ct * 16 + m_];
        f32x4 acc1[2] = { { nb1v, nb1v, nb1v, nb1v }, { nb1v, nb1v, nb1v, nb1v } };
#pragma unroll
        for (int tt = 0; tt < 2; tt++) {
            int mb = mbh * 2 + tt;
#pragma unroll
            for (int s = 0; s < 4; s++) {
                f16x8 hf = *(const f16x8*)(h_lds + (mb * 16 + m_) * LS + s * 32 + q_ * 8);
                f16x8 wf = *(const f16x8*)(Wslab + ((s * 8 + ct) * 64 + lane) * 8);
                acc1[tt] = __builtin_amdgcn_mfma_f32_16x16x32_f16(hf, wf, acc1[tt], 0, 0, 0);
            }
        }
        __syncthreads();
        stage_w(ptrs.p[6], lay * 32768 + 16384, bf, Wslab, t); // nw1 m-part
        __syncthreads();
#pragma unroll
        for (int tt = 0; tt < 2; tt++) {
            int mb = mbh * 2 + tt;
#pragma unroll
            for (int s = 0; s < 4; s++) {
                f16x8 mf = *(const f16x8*)(m_lds + (mb * 16 + m_) * LS + s * 32 + q_ * 8);
                f16x8 wf = *(const f16x8*)(Wslab + ((s * 8 + ct) * 64 + lane) * 8);
                acc1[tt] = __builtin_amdgcn_mfma_f32_16x16x32_f16(mf, wf, acc1[tt], 0, 0, 0);
            }
#pragma unroll
            for (int r = 0; r < 4; r++)
                a_lds[(mb * 16 + q_ * 4 + r) * LS + ct * 16 + m_] =
                    (f16)silu_f(acc1[tt][r]);      // u-relay (a dead after edge)
        }
        __syncthreads();
        stage_w(ptrs.p[8], lay * 16384, bf, Wslab, t);        // nw2
        __syncthreads();
        float nb2v = bias[256 + ct * 16 + m_];
        f32x4 acc2[2] = { { nb2v, nb2v, nb2v, nb2v }, { nb2v, nb2v, nb2v, nb2v } };
        float x[2][4];
#pragma unroll
        for (int tt = 0; tt < 2; tt++) {
            int mb = mbh * 2 + tt;
#pragma unroll
            for (int s = 0; s < 4; s++) {
                f16x8 uf = *(const f16x8*)(a_lds + (mb * 16 + m_) * LS + s * 32 + q_ * 8);
                f16x8 wf = *(const f16x8*)(Wslab + ((s * 8 + ct) * 64 + lane) * 8);
                acc2[tt] = __builtin_amdgcn_mfma_f32_16x16x32_f16(uf, wf, acc2[tt], 0, 0, 0);
            }
#pragma unroll
            for (int r = 0; r < 4; r++)
                x[tt][r] = acc2[tt][r] +
                    (float)h_lds[(mb * 16 + q_ * 4 + r) * LS + ct * 16 + m_];
        }
        // LN partials: reduce over this wave's 16 cols (m_ lanes)
        float s1p[2][4], s2p[2][4];
#pragma unroll
        for (int tt = 0; tt < 2; tt++)
#pragma unroll
            for (int r = 0; r < 4; r++) {
                s1p[tt][r] = x[tt][r];
                s2p[tt][r] = x[tt][r] * x[tt][r];
            }
#pragma unroll
        for (int msk = 1; msk < 16; msk <<= 1)
#pragma unroll
            for (int tt = 0; tt < 2; tt++)
#pragma unroll
                for (int r = 0; r < 4; r++) {
                    s1p[tt][r] += __shfl_xor(s1p[tt][r], msk);
                    s2p[tt][r] += __shfl_xor(s2p[tt][r], msk);
                }
        if (m_ == 0)
#pragma unroll
            for (int tt = 0; tt < 2; tt++)
#pragma unroll
                for (int r = 0; r < 4; r++) {
                    int row = (mbh * 2 + tt) * 16 + q_ * 4 + r;
                    s1sh[ct][row] = s1p[tt][r];
                    s2sh[ct][row] = s2p[tt][r];
                }
        __syncthreads();
        float lngv = bias[384 + ct * 16 + m_];
        float lnbv = bias[512 + ct * 16 + m_];

        if (lay < 3) {
#pragma unroll
            for (int tt = 0; tt < 2; tt++) {
                int mb = mbh * 2 + tt;
#pragma unroll
                for (int r = 0; r < 4; r++) {
                    int row = mb * 16 + q_ * 4 + r;
                    float S1 = 0.f, S2 = 0.f;
#pragma unroll
                    for (int c2 = 0; c2 < 8; c2++) { S1 += s1sh[c2][row]; S2 += s2sh[c2][row]; }
                    float mu = S1 * (1.0f / 128.0f);
                    float var = S2 * (1.0f / 128.0f) - mu * mu;
                    float rs = rsqrtf(var + 1e-5f);
                    float y = (x[tt][r] - mu) * rs * lngv + lnbv;
                    h_lds[row * LS + ct * 16 + m_] = (f16)y;
                }
            }
            __syncthreads();
            // next-layer a,b from h'
            stage_w(ptrs.p[2], (lay + 1) * 32896, bf, Wslab, t);       // wa
            __syncthreads();
            {
                float eb1nv = bias[640 + ct * 16 + m_];
                f32x4 acc[2];
#pragma unroll
                for (int tt = 0; tt < 2; tt++) {
                    acc[tt] = (f32x4){ eb1nv, eb1nv, eb1nv, eb1nv };
                    int mb = mbh * 2 + tt;
#pragma unroll
                    for (int s = 0; s < 4; s++) {
                        f16x8 hf = *(const f16x8*)(h_lds + (mb * 16 + m_) * LS + s * 32 + q_ * 8);
                        f16x8 wf = *(const f16x8*)(Wslab + ((s * 8 + ct) * 64 + lane) * 8);
                        acc[tt] = __builtin_amdgcn_mfma_f32_16x16x32_f16(hf, wf, acc[tt], 0, 0, 0);
                    }
#pragma unroll
                    for (int r = 0; r < 4; r++)
                        a_lds[(mb * 16 + q_ * 4 + r) * LS + ct * 16 + m_] = (f16)acc[tt][r];
                }
            }
            __syncthreads();
            stage_w(ptrs.p[2], (lay + 1) * 32896 + 16384, bf, Wslab, t); // wb
            __syncthreads();
            {
                f32x4 acc[2];
#pragma unroll
                for (int tt = 0; tt < 2; tt++) {
                    acc[tt] = (f32x4){ 0.f, 0.f, 0.f, 0.f };
                    int mb = mbh * 2 + tt;
#pragma unroll
                    for (int s = 0; s < 4; s++) {
                        f16x8 hf = *(const f16x8*)(h_lds + (mb * 16 + m_) * LS + s * 32 + q_ * 8);
                        f16x8 wf = *(const f16x8*)(Wslab + ((s * 8 + ct) * 64 + lane) * 8);
                        acc[tt] = __builtin_amdgcn_mfma_f32_16x16x32_f16(hf, wf, acc[tt], 0, 0, 0);
                    }
#pragma unroll
                    for (int r = 0; r < 4; r++)
                        b_lds[(mb * 16 + q_ * 4 + r) * LS + ct * 16 + m_] = (f16)acc[tt][r];
                }
            }
            __syncthreads();   // slab + b ready for next layer
        } else {
            // final: LN + out = y@ow + ob  (dsq dead -> psh overlay)
            float* psh = dsq_psh;          // [ct][row][k], 1536 floats
            float p[3][2][4];
#pragma unroll
            for (int tt = 0; tt < 2; tt++) {
                int mb = mbh * 2 + tt;
#pragma unroll
                for (int r = 0; r < 4; r++) {
                    int row = mb * 16 + q_ * 4 + r;
                    float S1 = 0.f, S2 = 0.f;
#pragma unroll
                    for (int c2 = 0; c2 < 8; c2++) { S1 += s1sh[c2][row]; S2 += s2sh[c2][row]; }
                    float mu = S1 * (1.0f / 128.0f);
                    float var = S2 * (1.0f / 128.0f) - mu * mu;
                    float rs = rsqrtf(var + 1e-5f);
                    float y = (x[tt][r] - mu) * rs * lngv + lnbv;
                    int col = ct * 16 + m_;
#pragma unroll
                    for (int k = 0; k < 3; k++)
                        p[k][tt][r] = y * ldf(ptrs.p[12], col * 3 + k, bf);
                }
            }
#pragma unroll
            for (int msk = 1; msk < 16; msk <<= 1)
#pragma unroll
                for (int k = 0; k < 3; k++)
#pragma unroll
                    for (int tt = 0; tt < 2; tt++)
#pragma unroll
                        for (int r = 0; r < 4; r++)
                            p[k][tt][r] += __shfl_xor(p[k][tt][r], msk);
            if (m_ == 0)
#pragma unroll
                for (int tt = 0; tt < 2; tt++)
#pragma unroll
                    for (int r = 0; r < 4; r++) {
                        int row = (mbh * 2 + tt) * 16 + q_ * 4 + r;
#pragma unroll
                        for (int k = 0; k < 3; k++)
                            psh[(ct * 64 + row) * 3 + k] = p[k][tt][r];
                    }
            __syncthreads();
            if (t < 192) {
                int row = t / 3, k = t - row * 3;
                float v = ldf(ptrs.p[13], k, bf);
#pragma unroll
                for (int c2 = 0; c2 < 8; c2++) v += psh[(c2 * 64 + row) * 3 + k];
                int grow = b * 64 + row;
                if (bf) ((unsigned short*)out)[grow * 3 + k] = f2bf(v);
                else    ((float*)out)[grow * 3 + k] = v;
            }
        }
    }
}

extern "C" void kernel_launch(void* const* d_in, const int* in_sizes, int n_in,
                              void* d_out, int out_size, void* d_ws, size_t ws_size,
                              hipStream_t stream)
{
    Ptrs ptrs;
    const int src_idx[14] = {0, 2, 3, 4, 5, 6, 7, 8, 9, 10, 11, 12, 13, 14};
    for (int k = 0; k < 14; k++) ptrs.p[k] = d_in[src_idx[k]];

    net_kernel<<<64, 1024, 0, stream>>>(ptrs, (const int*)d_in[1], d_out);
}

// Round 4
// 208.969 us; speedup vs baseline: 7.5567x; 7.5567x over previous
//
#include <hip/hip_runtime.h>
#include <hip/hip_fp16.h>

// B=64, N=64, D=128, L=4, T=10. Float tensors may arrive as bf16 OR fp32.
// r16: fused per-layer kernels at dispatch boundaries. Lessons:
//   r13: 10 small dispatches = 216us (overhead-dominated, kernels fast)
//   r14: persistent + agent-scope flag sync = L2 poison (FETCH 10.6MB, 12x
//        weight refetch) -> 211us net kernel
//   r15: 1 block/batch = 64 CUs only + per-block global W staging ->
//        FETCH 1.14GB, 1517us
// r16 = r14's fused dataflow (block = 16 rows; m in LDS; S built once per
// block in LDS) with dispatch boundaries instead of atomics. 6 dispatches:
// prep, embed, 4x layer. 256 blocks x 512 thr (all CUs). Only `b` crosses
// blocks -> global ping-pong across dispatches. Zero atomics/fences.

typedef _Float16 f16;
typedef _Float16 f16x8 __attribute__((ext_vector_type(8)));
typedef float f32x4 __attribute__((ext_vector_type(4)));

union H2x4 { f16x8 v; __half2 h[4]; };

__device__ __forceinline__ float bf2f(unsigned short u) {
    union { unsigned int i; float f; } v; v.i = ((unsigned int)u) << 16; return v.f;
}
__device__ __forceinline__ unsigned short f2bf(float f) {
    union { float f; unsigned int i; } v; v.f = f;
    unsigned int x = v.i;
    return (unsigned short)((x + 0x7fffu + ((x >> 16) & 1u)) >> 16);
}
__device__ __forceinline__ float silu_f(float x) {
    float e = __builtin_amdgcn_exp2f(-1.44269504088896f * x);
    return x * __builtin_amdgcn_rcpf(1.0f + e);
}
__device__ __forceinline__ __half2 silu_h2(__half2 x, __half2 kf, __half2 one2) {
    __half2 e = h2exp2(__hmul2(x, kf));
    return __hmul2(x, h2rcp(__hadd2(one2, e)));
}

struct Ptrs { const void* p[14]; };
// p: 0 pos, 1 embed, 2 ew1, 3 eb1, 4 ew2, 5 eb2, 6 nw1, 7 nb1, 8 nw2,
//    9 nb2, 10 lng, 11 lnb, 12 ow, 13 ob

__device__ __forceinline__ float ldf(const void* p, int i, int bf) {
    return bf ? bf2f(((const unsigned short*)p)[i]) : ((const float*)p)[i];
}

// small canon (fp32) offsets: pos 0(12288) embed 12288(1280) wd 13568(512)
// eb1 14080 eb2 14592 nb1 15104 nb2 15616 lng 16128 lnb 16640 (512 each)
// ow 17152(384) ob 17536(3). total 17539.
#define ELEM_TOTAL 393216
#define SMALL_TOTAL 17539

// Swizzle weights into f16 B-fragment order for mfma_f32_16x16x32_f16.
// dst[f*8+j] = W[rowoff + s*32 + ((l>>4)<<3) + j][c*16 + (l&15)], f=(s*8+c)*64+l.
// Per-layer frag bases (f16 elems): wa 0, wb 16384, ew2 32768, nw1 49152,
// nw2 81920; layer stride 98304.
__global__ __launch_bounds__(256) void prep_kernel(
    Ptrs ptrs, f16* dst, float* sc)
{
    __shared__ int flgsh;
    int t = threadIdx.x;
    if (t < 64) {
        int ex = (((const unsigned short*)ptrs.p[0])[t * 2] >> 7) & 0xFF;
        unsigned long long m = __ballot(ex >= 110 && ex <= 135);
        if (t == 0) flgsh = (__popcll(m) >= 40) ? 1 : 0;
    }
    __syncthreads();
    int bf = flgsh;

    int gid = blockIdx.x * 256 + t;
    if (gid < ELEM_TOTAL) {
        int f = gid >> 3, j = gid & 7;
        int lay = f / 12288;
        int r   = f % 12288;
        const void* src; int base, rowoff = 0, r2;
        if (r < 6144) {
            int mat = r >> 11; r2 = r & 2047;
            if (mat == 0)      { src = ptrs.p[2]; base = lay * 32896; }
            else if (mat == 1) { src = ptrs.p[2]; base = lay * 32896; rowoff = 128; }
            else               { src = ptrs.p[4]; base = lay * 16384; }
        } else if (r < 10240) {
            r2 = r - 6144; src = ptrs.p[6]; base = lay * 32768;
        } else {
            r2 = r - 10240; src = ptrs.p[8]; base = lay * 16384;
        }
        int s = r2 >> 9, c = (r2 >> 6) & 7, l = r2 & 63;
        int row = rowoff + s * 32 + ((l >> 4) << 3) + j;
        int col = (c << 4) + (l & 15);
        dst[gid] = (f16)ldf(src, base + row * 128 + col, bf);
    } else {
        int sid = gid - ELEM_TOTAL;
        if (sid >= SMALL_TOTAL) return;
        const void* src; int i;
        if      (sid < 12288) { src = ptrs.p[0]; i = sid; }
        else if (sid < 13568) { src = ptrs.p[1]; i = sid - 12288; }
        else if (sid < 14080) { int k = sid - 13568;
                                src = ptrs.p[2]; i = (k >> 7) * 32896 + 32768 + (k & 127); }
        else if (sid < 14592) { src = ptrs.p[3];  i = sid - 14080; }
        else if (sid < 15104) { src = ptrs.p[5];  i = sid - 14592; }
        else if (sid < 15616) { src = ptrs.p[7];  i = sid - 15104; }
        else if (sid < 16128) { src = ptrs.p[9];  i = sid - 15616; }
        else if (sid < 16640) { src = ptrs.p[10]; i = sid - 16128; }
        else if (sid < 17152) { src = ptrs.p[11]; i = sid - 16640; }
        else if (sid < 17536) { src = ptrs.p[12]; i = sid - 17152; }
        else                  { src = ptrs.p[13]; i = sid - 17536; }
        sc[sid] = ldf(src, i, bf);
    }
}

// h = embed[an]; a = h@wa + eb1; b = h@wb. (r13-proven, 512 thr, c = w)
__global__ __launch_bounds__(512) void embed_ab_kernel(
    const int* an, const float* sc, const f16* wa, const f16* wb,
    const float* eb1C, f16* h16, f16* a16, f16* b16)
{
    int t = threadIdx.x;
    int w = t >> 6, lane = t & 63;
    int row0 = blockIdx.x << 4;
    int m_ = lane & 15, q_ = lane >> 4;
    const float* emb = sc + 12288;
    int a = an[row0 + m_];
    a = a < 0 ? 0 : (a > 9 ? 9 : a);
    f16x8 afrag[4];
#pragma unroll
    for (int s = 0; s < 4; s++) {
        f32x4 u0 = *(const f32x4*)(emb + a * 128 + s * 32 + q_ * 8);
        f32x4 u1 = *(const f32x4*)(emb + a * 128 + s * 32 + q_ * 8 + 4);
        f16x8 hv;
#pragma unroll
        for (int e = 0; e < 4; e++) { hv[e] = (f16)u0[e]; hv[e + 4] = (f16)u1[e]; }
        afrag[s] = hv;
        if (w == 0)
            *(f16x8*)(h16 + (row0 + m_) * 128 + s * 32 + q_ * 8) = hv;
    }
    int c = w;
#pragma unroll
    for (int mat = 0; mat < 2; mat++) {
        const f16* W = mat ? wb : wa;
        f16* out     = mat ? b16 : a16;
        float init = mat ? 0.0f : eb1C[c * 16 + m_];
        f32x4 acc = { init, init, init, init };
#pragma unroll
        for (int s = 0; s < 4; s++) {
            f16x8 bfr = *(const f16x8*)(W + ((s * 8 + c) * 64 + lane) * 8);
            acc = __builtin_amdgcn_mfma_f32_16x16x32_f16(afrag[s], bfr, acc, 0, 0, 0);
        }
#pragma unroll
        for (int r = 0; r < 4; r++)
            out[(row0 + q_ * 4 + r) * 128 + c * 16 + m_] = (f16)acc[r];
    }
}

// Fused edge+node for one layer. Block = (batch b, part): rows r0..r0+15.
// 512 threads, 8 waves, wave w owns output col tile c = w.
// Edge: loop own 16 i; S_i built cooperatively in LDS (double-buffered,
// 1 barrier/i); ew2 fragments held in registers; m -> LDS only.
// Node: r13 node_mid math (h from global, m from LDS); writes h', a (own
// rows, in-place: block-private) and b (own rows) into bnxt (ping-pong).
__global__ __launch_bounds__(512) void layer_kernel(
    const void* pos_raw, const float* sc, const f16* Wswz, int lay,
    f16* h16, f16* a16, const f16* bcur, f16* bnxt, void* out)
{
    __shared__ f16 S[2][64 * 136];      // 34 KB; S[0] reused as node relay
    __shared__ f16 b_lds[64 * 136];     // 17 KB
    __shared__ f16 m_lds[16 * 136];
    __shared__ __half dsqh[1024];       // [i][j]
    __shared__ __half2 wd2_sh[64];
    __shared__ float s1sh[8][16], s2sh[8][16];
    __shared__ float psh[8][16][3];
    __shared__ int flgsh;

    int t = threadIdx.x;
    int w = t >> 6, lane = t & 63;
    int m_ = lane & 15, q_ = lane >> 4;
    int c = w;
    int b  = blockIdx.x >> 2;
    int r0 = b * 64 + (blockIdx.x & 3) * 16;
    const int fin = (lay == 3);

    const f16* wl   = Wswz + lay * 98304;
    const f16* ew2s = wl + 32768;
    const f16* nw1s = wl + 49152;
    const f16* nw2s = wl + 81920;
    const float* posC = sc;
    const float* wdC  = sc + 13568 + lay * 128;
    const float* eb2C = sc + 14592 + lay * 128;
    const float* nb1C = sc + 15104 + lay * 128;
    const float* nb2C = sc + 15616 + lay * 128;
    const float* lngC = sc + 16128 + lay * 128;
    const float* lnbC = sc + 16640 + lay * 128;

    if (t < 64) {
        int ex = (((const unsigned short*)pos_raw)[t * 2] >> 7) & 0xFF;
        unsigned long long mk = __ballot(ex >= 110 && ex <= 135);
        if (t == 0) flgsh = (__popcll(mk) >= 40) ? 1 : 0;
    }

    // ---- stage: b tile, dsq, wd ----
#pragma unroll
    for (int kk = 0; kk < 2; kk++) {
        int k = t + 512 * kk;
        int j = k >> 4, col0 = (k & 15) * 8;
        *(f16x8*)(b_lds + j * 136 + col0) =
            *(const f16x8*)(bcur + (b * 64 + j) * 128 + col0);
    }
#pragma unroll
    for (int kk = 0; kk < 2; kk++) {
        int k = t + 512 * kk;
        int i = k >> 6, j = k & 63;
        int gi = r0 + i, gj = b * 64 + j;
        float dx = posC[gi * 3 + 0] - posC[gj * 3 + 0];
        float dy = posC[gi * 3 + 1] - posC[gj * 3 + 1];
        float dz = posC[gi * 3 + 2] - posC[gj * 3 + 2];
        dsqh[k] = __float2half_rn(dx * dx + dy * dy + dz * dz);
    }
    if (t < 64) wd2_sh[t] = __floats2half2_rn(wdC[2 * t], wdC[2 * t + 1]);

    // per-wave edge constants
    f16x8 bfr[4];
#pragma unroll
    for (int s = 0; s < 4; s++)
        bfr[s] = *(const f16x8*)(ew2s + ((s * 8 + c) * 64 + lane) * 8);
    float eb2v = eb2C[c * 16 + m_];
    const __half2 kf   = __floats2half2_rn(-1.44269504f, -1.44269504f);
    const __half2 one2 = __floats2half2_rn(1.0f, 1.0f);
    __syncthreads();

    // S build: thread covers 2 chunks (row j, 8 cols)
#define BUILD_S(I, SD)                                                        \
    {                                                                         \
        _Pragma("unroll")                                                     \
        for (int kk = 0; kk < 2; kk++) {                                      \
            int k = t + 512 * kk;                                             \
            int j = k >> 4, col0 = (k & 15) * 8;                              \
            __half dh = dsqh[(I) * 64 + j];                                   \
            __half2 ds2 = __halves2half2(dh, dh);                             \
            H2x4 av, bv, wv, sv;                                              \
            av.v = *(const f16x8*)(a16 + (r0 + (I)) * 128 + col0);            \
            bv.v = *(const f16x8*)(b_lds + j * 136 + col0);                   \
            wv.v = *(const f16x8*)((const f16*)wd2_sh + col0);                \
            _Pragma("unroll")                                                 \
            for (int e = 0; e < 4; e++) {                                     \
                __half2 pre = __hfma2(ds2, wv.h[e],                           \
                                      __hadd2(av.h[e], bv.h[e]));             \
                sv.h[e] = silu_h2(pre, kf, one2);                             \
            }                                                                 \
            *(f16x8*)((SD) + j * 136 + col0) = sv.v;                          \
        }                                                                     \
    }

    BUILD_S(0, S[0]);
    __syncthreads();

    // ---- edge loop over own 16 i ----
#pragma unroll 1
    for (int i = 0; i < 16; i++) {
        if (i < 15) BUILD_S(i + 1, S[(i + 1) & 1]);
        const f16* Sc = S[i & 1];
        f32x4 acc[4];
#pragma unroll
        for (int mb = 0; mb < 4; mb++)
            acc[mb] = (f32x4){ eb2v, eb2v, eb2v, eb2v };
#pragma unroll
        for (int s = 0; s < 4; s++)
#pragma unroll
            for (int mb = 0; mb < 4; mb++) {
                f16x8 af = *(const f16x8*)(Sc + (mb * 16 + m_) * 136 + s * 32 + q_ * 8);
                acc[mb] = __builtin_amdgcn_mfma_f32_16x16x32_f16(af, bfr[s], acc[mb], 0, 0, 0);
            }
        float red = 0.0f;
#pragma unroll
        for (int mb = 0; mb < 4; mb++)
#pragma unroll
            for (int r = 0; r < 4; r++)
                red += silu_f(acc[mb][r]);
        red += __shfl_xor(red, 16);
        red += __shfl_xor(red, 32);
        if (q_ == 0)
            m_lds[i * 136 + c * 16 + m_] = (f16)(red * 0.015625f);
        __syncthreads();
    }

    // ---- node (r13 node_mid math; m from LDS) ----
    f16x8 af2[8];
#pragma unroll
    for (int s = 0; s < 4; s++) {
        af2[s]     = *(const f16x8*)(h16 + (r0 + m_) * 128 + s * 32 + q_ * 8);
        af2[s + 4] = *(const f16x8*)(m_lds + m_ * 136 + s * 32 + q_ * 8);
    }
    f16* relay = &S[0][0];
    {
        float e = nb1C[c * 16 + m_];
        f32x4 acc = { e, e, e, e };
#pragma unroll
        for (int s = 0; s < 8; s++) {
            f16x8 bv = *(const f16x8*)(nw1s + ((s * 8 + c) * 64 + lane) * 8);
            acc = __builtin_amdgcn_mfma_f32_16x16x32_f16(af2[s], bv, acc, 0, 0, 0);
        }
#pragma unroll
        for (int r = 0; r < 4; r++)
            relay[(q_ * 4 + r) * 136 + c * 16 + m_] = (f16)silu_f(acc[r]);
    }
    __syncthreads();
    f16x8 uf[4];
#pragma unroll
    for (int s = 0; s < 4; s++)
        uf[s] = *(const f16x8*)(relay + m_ * 136 + s * 32 + q_ * 8);
    float x[4];
    {
        float e = nb2C[c * 16 + m_];
        f32x4 acc = { e, e, e, e };
#pragma unroll
        for (int s = 0; s < 4; s++) {
            f16x8 bv = *(const f16x8*)(nw2s + ((s * 8 + c) * 64 + lane) * 8);
            acc = __builtin_amdgcn_mfma_f32_16x16x32_f16(uf[s], bv, acc, 0, 0, 0);
        }
#pragma unroll
        for (int r = 0; r < 4; r++)
            x[r] = acc[r] + (float)h16[(r0 + q_ * 4 + r) * 128 + c * 16 + m_];
    }
    float s1p[4], s2p[4];
#pragma unroll
    for (int r = 0; r < 4; r++) { s1p[r] = x[r]; s2p[r] = x[r] * x[r]; }
#pragma unroll
    for (int msk = 1; msk < 16; msk <<= 1)
#pragma unroll
        for (int r = 0; r < 4; r++) {
            s1p[r] += __shfl_xor(s1p[r], msk);
            s2p[r] += __shfl_xor(s2p[r], msk);
        }
    if (m_ == 0)
#pragma unroll
        for (int r = 0; r < 4; r++) {
            s1sh[w][q_ * 4 + r] = s1p[r];
            s2sh[w][q_ * 4 + r] = s2p[r];
        }
    __syncthreads();
    float mu[4], rs[4];
#pragma unroll
    for (int r = 0; r < 4; r++) {
        int row = q_ * 4 + r;
        float S1 = 0.f, S2 = 0.f;
#pragma unroll
        for (int w2 = 0; w2 < 8; w2++) { S1 += s1sh[w2][row]; S2 += s2sh[w2][row]; }
        mu[r] = S1 * (1.0f / 128.0f);
        float var = S2 * (1.0f / 128.0f) - mu[r] * mu[r];
        rs[r] = rsqrtf(var + 1e-5f);
    }

    if (!fin) {
#pragma unroll
        for (int r = 0; r < 4; r++) {
            int col = c * 16 + m_;
            int row = r0 + q_ * 4 + r;
            float y = (x[r] - mu[r]) * rs[r] * lngC[col] + lnbC[col];
            h16[row * 128 + col] = (f16)y;
            relay[(q_ * 4 + r) * 136 + col] = (f16)y;
        }
        __syncthreads();
        f16x8 hf[4];
#pragma unroll
        for (int s = 0; s < 4; s++)
            hf[s] = *(const f16x8*)(relay + m_ * 136 + s * 32 + q_ * 8);
        const f16* wlN = Wswz + (lay + 1) * 98304;
        const float* eb1N = sc + 14080 + (lay + 1) * 128;
#pragma unroll
        for (int mat = 0; mat < 2; mat++) {
            const f16* W = mat ? (wlN + 16384) : wlN;
            float init = mat ? 0.0f : eb1N[c * 16 + m_];
            f32x4 acc = { init, init, init, init };
#pragma unroll
            for (int s = 0; s < 4; s++) {
                f16x8 bv = *(const f16x8*)(W + ((s * 8 + c) * 64 + lane) * 8);
                acc = __builtin_amdgcn_mfma_f32_16x16x32_f16(hf[s], bv, acc, 0, 0, 0);
            }
#pragma unroll
            for (int r = 0; r < 4; r++) {
                if (mat == 0)
                    a16[(r0 + q_ * 4 + r) * 128 + c * 16 + m_] = (f16)acc[r];
                else
                    bnxt[(r0 + q_ * 4 + r) * 128 + c * 16 + m_] = (f16)acc[r];
            }
        }
    } else {
        const float* owC = sc + 17152;
        const float* obC = sc + 17536;
        float p[3][4];
#pragma unroll
        for (int r = 0; r < 4; r++) {
            int col = c * 16 + m_;
            float y = (x[r] - mu[r]) * rs[r] * lngC[col] + lnbC[col];
            p[0][r] = y * owC[col * 3 + 0];
            p[1][r] = y * owC[col * 3 + 1];
            p[2][r] = y * owC[col * 3 + 2];
        }
#pragma unroll
        for (int msk = 1; msk < 16; msk <<= 1)
#pragma unroll
            for (int k = 0; k < 3; k++)
#pragma unroll
                for (int r = 0; r < 4; r++)
                    p[k][r] += __shfl_xor(p[k][r], msk);
        if (m_ == 0)
#pragma unroll
            for (int r = 0; r < 4; r++)
#pragma unroll
                for (int k = 0; k < 3; k++)
                    psh[w][q_ * 4 + r][k] = p[k][r];
        __syncthreads();
        if (t < 16) {
            int row = r0 + t;
            int bf = flgsh;
#pragma unroll
            for (int k = 0; k < 3; k++) {
                float v = obC[k];
#pragma unroll
                for (int w2 = 0; w2 < 8; w2++) v += psh[w2][t][k];
                if (bf) ((unsigned short*)out)[row * 3 + k] = f2bf(v);
                else    ((float*)out)[row * 3 + k] = v;
            }
        }
    }
}

extern "C" void kernel_launch(void* const* d_in, const int* in_sizes, int n_in,
                              void* d_out, int out_size, void* d_ws, size_t ws_size,
                              hipStream_t stream)
{
    char* ws = (char*)d_ws;
    float* sc   = (float*)(ws + 1024);              // 70 KB
    f16*   Wswz = (f16*)(ws + (128u << 10));        // 768 KB
    f16*   h16  = (f16*)(ws + (1u << 20));
    f16*   a16  = (f16*)(ws + (2u << 20));
    f16*   b0   = (f16*)(ws + (3u << 20));
    f16*   b1   = (f16*)(ws + (4u << 20));          // total 5 MB

    Ptrs ptrs;
    const int src_idx[14] = {0, 2, 3, 4, 5, 6, 7, 8, 9, 10, 11, 12, 13, 14};
    for (int k = 0; k < 14; k++) ptrs.p[k] = d_in[src_idx[k]];

    prep_kernel<<<1605, 256, 0, stream>>>(ptrs, Wswz, sc);
    embed_ab_kernel<<<256, 512, 0, stream>>>((const int*)d_in[1], sc, Wswz,
                                             Wswz + 16384, sc + 14080,
                                             h16, a16, b0);
    for (int lay = 0; lay < 4; lay++) {
        const f16* bcur = (lay & 1) ? b1 : b0;
        f16*       bnxt = (lay & 1) ? b0 : b1;
        layer_kernel<<<256, 512, 0, stream>>>(d_in[0], sc, Wswz, lay,
                                              h16, a16, bcur, bnxt, d_out);
    }
}